// Round 9
// baseline (211.317 us; speedup 1.0000x reference)
//
#include <hip/hip_runtime.h>
#include <hip/hip_bf16.h>

// B=2, S=2048, D=1024, H=16, DK=64, THETA=10000
// Inputs fp32 (positions int32): x[2,2048,1024], token_positions[2048],
// Wq,Wk,Wv,Wo [1024,1024].  Output fp32 [2,2048,1024].
// proj: y[b,s,o] = sum_d x[b,s,d] * W[o,d]

typedef __attribute__((ext_vector_type(8))) short short8;   // 8 bf16 = 4 VGPRs
typedef __attribute__((ext_vector_type(4))) float floatx4;  // MFMA accumulator

static __device__ __forceinline__ unsigned short f2bf(float f) {
  __hip_bfloat16 h = __float2bfloat16(f);
  return *(unsigned short*)&h;
}

// pack 2 floats -> 2 bf16 in one u32 (half-up rounding + v_perm byte pick).
// low ushort = bf16(a), high ushort = bf16(b). Finite inputs only.
static __device__ __forceinline__ unsigned int pk2bf(float a, float b) {
  unsigned int ua = __float_as_uint(a) + 0x8000u;
  unsigned int ub = __float_as_uint(b) + 0x8000u;
  return __builtin_amdgcn_perm(ub, ua, 0x07060302u);
}

// raw v_exp_f32 (2^x), single VALU transcendental; s_nop covers the
// trans->VALU dependency wait state.
static __device__ __forceinline__ float fexp2(float x) {
  float r;
  asm("v_exp_f32 %0, %1\n\ts_nop 0" : "=v"(r) : "v"(x));
  return r;
}

// async global->LDS DMA, 16 B per lane; lds base must be wave-uniform,
// HW writes lane i at ldsbase + i*16.
static __device__ __forceinline__ void gl2lds16(const unsigned short* g,
                                                unsigned short* l) {
  __builtin_amdgcn_global_load_lds(
      (const __attribute__((address_space(1))) void*)g,
      (__attribute__((address_space(3))) void*)l, 16, 0, 0);
}

// ---------------------------------------------------------------------------
// fp32 -> bf16 conversion for all 5 tensors + RoPE table gen, one launch.
// blockIdx.y: 0=x 1=Wq 2=Wk 3=Wv 4=Wo 5=rope tables
// ---------------------------------------------------------------------------
__global__ __launch_bounds__(256) void cvt_all(
    const float4* __restrict__ x,  const float4* __restrict__ wq,
    const float4* __restrict__ wk, const float4* __restrict__ wv,
    const float4* __restrict__ wo,
    ushort4* __restrict__ xb,  ushort4* __restrict__ wqb,
    ushort4* __restrict__ wkb, ushort4* __restrict__ wvb,
    ushort4* __restrict__ wob,
    const int* __restrict__ tokpos,
    float* __restrict__ ctab, float* __restrict__ stab) {
  int t = blockIdx.y;
  int i = blockIdx.x * 256 + threadIdx.x;
  if (t == 5) {
    if (i < 65536) {     // 2048 positions x 32 pair-freqs
      int s = i >> 5, f = i & 31;
      float inv = expf(-9.210340371976184f * (float)(2 * f) / 64.0f);
      float ang = (float)tokpos[s] * inv;
      ctab[i] = cosf(ang);
      stab[i] = sinf(ang);
    }
    return;
  }
  const float4* s = (t == 0) ? x : (t == 1) ? wq : (t == 2) ? wk : (t == 3) ? wv : wo;
  ushort4* d = (t == 0) ? xb : (t == 1) ? wqb : (t == 2) ? wkb : (t == 3) ? wvb : wob;
  int n4 = (t == 0) ? 1048576 : 262144;
  if (i < n4) {
    float4 v = s[i];
    ushort4 o;
    o.x = f2bf(v.x); o.y = f2bf(v.y); o.z = f2bf(v.z); o.w = f2bf(v.w);
    d[i] = o;
  }
}

// ---------------------------------------------------------------------------
// QKV projection R17: 64x128 tiles, depth-2 counted-vmcnt DMA pipeline +
// XCD panel clustering (t = bx + 64*by; XCD = t%8 = logical n-panel; each
// XCD serves ONE 128-col W panel per matrix -> W L2-resident).  Measured
// R8: qkv left top-5.
// Pipeline per K-step (6 DMA loads/thread/tile):
//   compute(slot kt&1); s_barrier(A); issue L(kt+2)->slot kt&1;
//   s_waitcnt vmcnt(6) [retires L(kt+1) only]; s_barrier(B)
// LDS 48KB -> 3 blocks/CU; grid 64x8x3 = 1536 = 2 uniform rounds.
// Q pre-scaled by (1/sqrt(64))*log2(e); Q,K [bh][s][64]; V^T [bh][d][2048].
// ---------------------------------------------------------------------------
__global__ __launch_bounds__(256) void qkv_mfma(
    const unsigned short* __restrict__ X,
    const unsigned short* __restrict__ Wq,
    const unsigned short* __restrict__ Wk,
    const unsigned short* __restrict__ Wv,
    const float* __restrict__ ctab, const float* __restrict__ stab,
    unsigned short* __restrict__ Qo, unsigned short* __restrict__ Ko,
    unsigned short* __restrict__ Vo) {
  int mat = blockIdx.z;  // 0=q 1=k 2=v
  const unsigned short* W = (mat == 0) ? Wq : ((mat == 1) ? Wk : Wv);
  unsigned short* Out = (mat == 0) ? Qo : ((mat == 1) ? Ko : Vo);
  int t = blockIdx.x + (blockIdx.y << 6);   // 0..511
  int m0 = (t >> 3) * 64, n0 = (t & 7) * 128;

  __shared__ __align__(16) unsigned short lA[2][64 * 64];
  __shared__ __align__(16) unsigned short lB[2][128 * 64];
  int tid = threadIdx.x;
  int wave = tid >> 6, lane = tid & 63;
  int l15 = lane & 15, quad = lane >> 4;
  int rsub = lane >> 3, sch = lane & 7;
  int fsw = l15 & 7;

  floatx4 acc[4][2];
#pragma unroll
  for (int m = 0; m < 4; ++m)
#pragma unroll
    for (int n = 0; n < 2; ++n) acc[m][n] = (floatx4){0.f, 0.f, 0.f, 0.f};

  // prologue: L(0)->slot0 (6 loads), L(1)->slot1 (6 loads)
#pragma unroll
  for (int kp = 0; kp < 2; ++kp) {
#pragma unroll
    for (int p = 0; p < 2; ++p) {
      int r = wave * 16 + p * 8 + rsub;
      int g = sch ^ (r & 7);
      gl2lds16(X + (size_t)(m0 + r) * 1024 + kp * 64 + g * 8,
               lA[kp] + (wave * 16 + p * 8) * 64);
    }
#pragma unroll
    for (int p = 0; p < 4; ++p) {
      int r = wave * 32 + p * 8 + rsub;
      int g = sch ^ (r & 7);
      gl2lds16(W + (size_t)(n0 + r) * 1024 + kp * 64 + g * 8,
               lB[kp] + (wave * 32 + p * 8) * 64);
    }
  }
  asm volatile("s_waitcnt vmcnt(6)" ::: "memory");  // L(0) done
  __builtin_amdgcn_s_barrier();

  for (int kt = 0; kt < 16; ++kt) {
    int cur = kt & 1;
#pragma unroll
    for (int ks = 0; ks < 2; ++ks) {
      int slot = ((ks * 4 + quad) ^ fsw) * 8;
      short8 af[4], bf[2];
#pragma unroll
      for (int m = 0; m < 4; ++m)
        af[m] = *(const short8*)(lA[cur] + (m * 16 + l15) * 64 + slot);
#pragma unroll
      for (int n = 0; n < 2; ++n)
        bf[n] = *(const short8*)(lB[cur] + (wave * 32 + n * 16 + l15) * 64 + slot);
#pragma unroll
      for (int m = 0; m < 4; ++m)
#pragma unroll
        for (int n = 0; n < 2; ++n)
          acc[m][n] = __builtin_amdgcn_mfma_f32_16x16x32_bf16(
              af[m], bf[n], acc[m][n], 0, 0, 0);
    }
    if (kt == 15) break;
    __builtin_amdgcn_s_barrier();  // (A)
    if (kt < 14) {
#pragma unroll
      for (int p = 0; p < 2; ++p) {
        int r = wave * 16 + p * 8 + rsub;
        int g = sch ^ (r & 7);
        gl2lds16(X + (size_t)(m0 + r) * 1024 + (kt + 2) * 64 + g * 8,
                 lA[cur] + (wave * 16 + p * 8) * 64);
      }
#pragma unroll
      for (int p = 0; p < 4; ++p) {
        int r = wave * 32 + p * 8 + rsub;
        int g = sch ^ (r & 7);
        gl2lds16(W + (size_t)(n0 + r) * 1024 + (kt + 2) * 64 + g * 8,
                 lB[cur] + (wave * 32 + p * 8) * 64);
      }
      asm volatile("s_waitcnt vmcnt(6)" ::: "memory");  // L(kt+1) done
    } else {
      asm volatile("s_waitcnt vmcnt(0)" ::: "memory");  // drain L(15)
    }
    __builtin_amdgcn_s_barrier();  // (B)
  }

  // ---- fused RoPE / transpose epilogue (wave owns 32 cols, 64 rows)
#pragma unroll
  for (int n = 0; n < 2; ++n) {
    int col = n0 + wave * 32 + n * 16 + l15;  // 0..1023
    int h = col >> 6;
    int d = col & 63;
    int pi = d >> 1;
    bool odd = (d & 1) != 0;
    size_t hb = (size_t)h * 2048 * 64;
#pragma unroll
    for (int m = 0; m < 4; ++m) {
      int row0 = m0 + m * 16 + quad * 4;  // rows row0..row0+3
      int b = row0 >> 11;
      int s0 = row0 & 2047;
      size_t base = (size_t)b * 16 * 2048 * 64 + hb;
      if (mat == 2) {
        // V: packed b64 store along s (transposed layout [d][s])
        ushort4 pv;
        pv.x = f2bf(acc[m][n][0]);
        pv.y = f2bf(acc[m][n][1]);
        pv.z = f2bf(acc[m][n][2]);
        pv.w = f2bf(acc[m][n][3]);
        *(ushort4*)(Out + base + (size_t)d * 2048 + s0) = pv;
      } else {
#pragma unroll
        for (int i = 0; i < 4; ++i) {
          int s = s0 + i;
          float v = acc[m][n][i];
          float p = __shfl_xor(v, 1);
          float c = ctab[s * 32 + pi];
          float sn = stab[s * 32 + pi];
          float res = odd ? fmaf(p, sn, v * c) : fmaf(v, c, -p * sn);
          if (mat == 0) res *= 0.1803368801111204f;  // 0.125 * log2(e)
          Out[base + (size_t)s * 64 + d] = f2bf(res);
        }
      }
    }
  }
}

// ---------------------------------------------------------------------------
// Output projection R17: out = Oc @ Wo^T.  64x128 tiles, depth-2 pipeline,
// XCD panel clustering (Wo panel 256KB L2-resident per XCD).  fp32 store.
// ---------------------------------------------------------------------------
__global__ __launch_bounds__(256) void oproj_mfma(
    const unsigned short* __restrict__ A, const unsigned short* __restrict__ Wo,
    float* __restrict__ Out) {
  __shared__ __align__(16) unsigned short lA[2][64 * 64];
  __shared__ __align__(16) unsigned short lB[2][128 * 64];
  int tid = threadIdx.x;
  int wave = tid >> 6, lane = tid & 63;
  int l15 = lane & 15, quad = lane >> 4;
  int rsub = lane >> 3, sch = lane & 7;
  int fsw = l15 & 7;
  int t = blockIdx.x + (blockIdx.y << 6);   // 0..511
  int m0 = (t >> 3) * 64, n0 = (t & 7) * 128;

  floatx4 acc[4][2];
#pragma unroll
  for (int m = 0; m < 4; ++m)
#pragma unroll
    for (int n = 0; n < 2; ++n) acc[m][n] = (floatx4){0.f, 0.f, 0.f, 0.f};

#pragma unroll
  for (int kp = 0; kp < 2; ++kp) {
#pragma unroll
    for (int p = 0; p < 2; ++p) {
      int r = wave * 16 + p * 8 + rsub;
      int g = sch ^ (r & 7);
      gl2lds16(A + (size_t)(m0 + r) * 1024 + kp * 64 + g * 8,
               lA[kp] + (wave * 16 + p * 8) * 64);
    }
#pragma unroll
    for (int p = 0; p < 4; ++p) {
      int r = wave * 32 + p * 8 + rsub;
      int g = sch ^ (r & 7);
      gl2lds16(Wo + (size_t)(n0 + r) * 1024 + kp * 64 + g * 8,
               lB[kp] + (wave * 32 + p * 8) * 64);
    }
  }
  asm volatile("s_waitcnt vmcnt(6)" ::: "memory");  // L(0) done
  __builtin_amdgcn_s_barrier();

  for (int kt = 0; kt < 16; ++kt) {
    int cur = kt & 1;
#pragma unroll
    for (int ks = 0; ks < 2; ++ks) {
      int slot = ((ks * 4 + quad) ^ fsw) * 8;
      short8 af[4], bf[2];
#pragma unroll
      for (int m = 0; m < 4; ++m)
        af[m] = *(const short8*)(lA[cur] + (m * 16 + l15) * 64 + slot);
#pragma unroll
      for (int n = 0; n < 2; ++n)
        bf[n] = *(const short8*)(lB[cur] + (wave * 32 + n * 16 + l15) * 64 + slot);
#pragma unroll
      for (int m = 0; m < 4; ++m)
#pragma unroll
        for (int n = 0; n < 2; ++n)
          acc[m][n] = __builtin_amdgcn_mfma_f32_16x16x32_bf16(
              af[m], bf[n], acc[m][n], 0, 0, 0);
    }
    if (kt == 15) break;
    __builtin_amdgcn_s_barrier();  // (A)
    if (kt < 14) {
#pragma unroll
      for (int p = 0; p < 2; ++p) {
        int r = wave * 16 + p * 8 + rsub;
        int g = sch ^ (r & 7);
        gl2lds16(A + (size_t)(m0 + r) * 1024 + (kt + 2) * 64 + g * 8,
                 lA[cur] + (wave * 16 + p * 8) * 64);
      }
#pragma unroll
      for (int p = 0; p < 4; ++p) {
        int r = wave * 32 + p * 8 + rsub;
        int g = sch ^ (r & 7);
        gl2lds16(Wo + (size_t)(n0 + r) * 1024 + (kt + 2) * 64 + g * 8,
                 lB[cur] + (wave * 32 + p * 8) * 64);
      }
      asm volatile("s_waitcnt vmcnt(6)" ::: "memory");  // L(kt+1) done
    } else {
      asm volatile("s_waitcnt vmcnt(0)" ::: "memory");  // drain L(15)
    }
    __builtin_amdgcn_s_barrier();  // (B)
  }

#pragma unroll
  for (int m = 0; m < 4; ++m) {
#pragma unroll
    for (int n = 0; n < 2; ++n) {
      int col = n0 + wave * 32 + n * 16 + l15;
#pragma unroll
      for (int i = 0; i < 4; ++i) {
        int row = m0 + m * 16 + quad * 4 + i;
        Out[(size_t)row * 1024 + col] = acc[m][n][i];
      }
    }
  }
}

// ---------------------------------------------------------------------------
// Flash attention R19: BARRIER-FREE 1-wave blocks, direct global->fragment.
// R8 diagnosis: attn pinned at 46.5us across 3 structural variants; wall =
// ~3490 cyc/iter vs ~600 issue.  Everything was coupled through the 2-wave
// barrier (lgkm drain + rendezvous + residency decay).  Key insight: in a
// 16-q-row wave, K/V fragment rows map EXACTLY to MFMA operand addresses --
// each element is read ONCE per wave, so LDS staging has zero intra-wave
// reuse; it only shared tiles between waves.  Drop the multi-wave block ->
// drop LDS K/V -> drop ALL barriers.  1-wave workgroups need no s_barrier;
// same-wave ds/vmem ordering + compiler-exact counted waits suffice.
//  - 2048 blocks x 64 thr: (bh, qtile, half).  id%8 = bh>>2 keeps XCD L2
//    clustering (FETCH 62->12MB, R4).  qt DESCENDING (long blocks first).
//  - Each wave: 2 streams (rows +0/+16 of its 32) SHARE the K/V fragments
//    -> L2 traffic unchanged (~540MB; ~16us at the 34.5TB/s L2 ceiling).
//  - K-frags direct from global at the same addresses staging used
//    ((sub*16+l15)*64 + quad*8 +/-32); V-frags from Vt[d][s].  Next-tile
//    prefetch issued right after last use -> full-iteration window (R7's
//    regression was a ~100cy window; this is ~600+).
//  - Only LDS: 4KB lP (verified XOR-swizzled P transpose, same-wave).
//  - launch_bounds(64,2): 256-VGPR headroom, 2048 slots = grid resident.
// ---------------------------------------------------------------------------
static __device__ __forceinline__ void sm_step(
    floatx4 (&sc)[4], float& m_i, float& l_i, floatx4 (&o)[4],
    bool diag, int qin, int quad) {
  if (diag) {  // causal mask on diagonal tile: k-within > q-within
#pragma unroll
    for (int sub = 0; sub < 4; ++sub)
#pragma unroll
      for (int i = 0; i < 4; ++i)
        if (sub * 16 + quad * 4 + i > qin) sc[sub][i] = -1e30f;
  }
  float mb = sc[0][0];
#pragma unroll
  for (int sub = 0; sub < 4; ++sub)
#pragma unroll
    for (int i = 0; i < 4; ++i) mb = fmaxf(mb, sc[sub][i]);
  mb = fmaxf(mb, __shfl_xor(mb, 16));
  mb = fmaxf(mb, __shfl_xor(mb, 32));

  // T13 defer-max: rescale only when some lane's max grew by > 8 (log2
  // domain, P <= 2^8; fp32 l/o headroom ample; normalized at epilogue).
  if (!__all(mb <= m_i + 8.f)) {
    float mn = fmaxf(m_i, mb);
    float al = fexp2(m_i - mn);
    m_i = mn;
    l_i *= al;
#pragma unroll
    for (int n = 0; n < 4; ++n) {
      o[n][0] *= al; o[n][1] *= al; o[n][2] *= al; o[n][3] *= al;
    }
  }
  float rs = 0.f;
#pragma unroll
  for (int sub = 0; sub < 4; ++sub)
#pragma unroll
    for (int i = 0; i < 4; ++i) {
      float p = fexp2(sc[sub][i] - m_i);
      sc[sub][i] = p;
      rs += p;
    }
  rs += __shfl_xor(rs, 16);
  rs += __shfl_xor(rs, 32);
  l_i += rs;
}

// P^T transpose through XOR-swizzled lP row (q=l15), then PV MFMA with
// register V-fragments.  Write: k = sub*16+quad*4+i -> 16B slot
// sub*2+(quad>>1) (8B half quad&1) at slot^(l15&7).  Read: pa0 =
// k[quad*8..+8) -> slot quad^(l15&7); pa1 = k[32+quad*8..+8) -> slot
// (4+quad)^(l15&7).  Same-wave DS ordering: no barrier needed.
static __device__ __forceinline__ void pv_reg(
    const floatx4 (&sc)[4], floatx4 (&o)[4], unsigned short* lPs,
    const short8 (&v0)[4], const short8 (&v1)[4], int l15, int quad) {
  int swz = l15 & 7;
  unsigned short* pw = lPs + l15 * 64;
#pragma unroll
  for (int sub = 0; sub < 4; ++sub) {
    uint2 w;
    w.x = pk2bf(sc[sub][0], sc[sub][1]);
    w.y = pk2bf(sc[sub][2], sc[sub][3]);
    int slot = (sub * 2 + (quad >> 1)) ^ swz;
    *(uint2*)(pw + slot * 8 + (quad & 1) * 4) = w;
  }
  short8 pa0 = *(const short8*)(pw + ((quad ^ swz) * 8));
  short8 pa1 = *(const short8*)(pw + (((4 + quad) ^ swz) * 8));
#pragma unroll
  for (int n = 0; n < 4; ++n) {
    o[n] = __builtin_amdgcn_mfma_f32_16x16x32_bf16(v0[n], pa0, o[n], 0, 0, 0);
    o[n] = __builtin_amdgcn_mfma_f32_16x16x32_bf16(v1[n], pa1, o[n], 0, 0, 0);
  }
}

__global__ __launch_bounds__(64, 2) void attn_flash(
    const unsigned short* __restrict__ Q, const unsigned short* __restrict__ K,
    const unsigned short* __restrict__ Vt, unsigned short* __restrict__ Oc) {
  __shared__ __align__(16) unsigned short lP[2][16 * 64];  // per-stream, 4KB

  int lane = threadIdx.x;
  int l15 = lane & 15, quad = lane >> 4;

  // decode: id%8 = XCD = bh>>2; qt descending (longest blocks first)
  int id = blockIdx.x;                   // 0..2047
  int bh = (id & 7) * 4 + ((id >> 3) & 3);
  int rest = id >> 5;                    // 0..63
  int qt = 31 - (rest >> 1);
  int h = rest & 1;                      // which 32-row half of the tile
  int NT = qt + 1;

  size_t base = (size_t)bh * 2048 * 64;

  // Q fragments, two 16-row streams (rows h*32+0..16 and +16..32)
  const unsigned short* qr = Q + base + (size_t)(qt * 64 + h * 32 + l15) * 64;
  short8 qA0 = *(const short8*)(qr + quad * 8);
  short8 qA1 = *(const short8*)(qr + 32 + quad * 8);
  short8 qB0 = *(const short8*)(qr + 16 * 64 + quad * 8);
  short8 qB1 = *(const short8*)(qr + 16 * 64 + 32 + quad * 8);

  int qinA = h * 32 + l15;
  int qinB = qinA + 16;

  floatx4 oA[4], oB[4];
  float mA = -1e30f, lA = 0.f, mB = -1e30f, lB = 0.f;
#pragma unroll
  for (int n = 0; n < 4; ++n) {
    oA[n] = (floatx4){0.f, 0.f, 0.f, 0.f};
    oB[n] = (floatx4){0.f, 0.f, 0.f, 0.f};
  }

  const unsigned short* Kg = K + base;
  const unsigned short* Vg = Vt + base;
  int kO = l15 * 64 + quad * 8;              // K: row l15 (+16*sub), chunk quad
  size_t vO = (size_t)l15 * 2048 + quad * 8; // V^T: d row l15 (+16*n)

  short8 k0[4], k1[4], v0[4], v1[4];
  // prologue: load tile kt=0 fragments
#pragma unroll
  for (int sub = 0; sub < 4; ++sub) {
    const unsigned short* kp = Kg + sub * 1024 + kO;
    k0[sub] = *(const short8*)(kp);
    k1[sub] = *(const short8*)(kp + 32);
  }
#pragma unroll
  for (int n = 0; n < 4; ++n) {
    const unsigned short* vp = Vg + (size_t)n * 16 * 2048 + vO;
    v0[n] = *(const short8*)(vp);
    v1[n] = *(const short8*)(vp + 32);
  }

  for (int kt = 0; kt < NT; ++kt) {
    int ktn = (kt + 1 < NT) ? kt + 1 : kt;  // clamped: tail loads redundant

    // ---- QK both streams (consume k0/k1; streams share K-frags)
    floatx4 scA[4], scB[4];
#pragma unroll
    for (int sub = 0; sub < 4; ++sub) {
      floatx4 z = {0.f, 0.f, 0.f, 0.f};
      floatx4 sA = __builtin_amdgcn_mfma_f32_16x16x32_bf16(k0[sub], qA0, z, 0, 0, 0);
      scA[sub] = __builtin_amdgcn_mfma_f32_16x16x32_bf16(k1[sub], qA1, sA, 0, 0, 0);
      floatx4 sB = __builtin_amdgcn_mfma_f32_16x16x32_bf16(k0[sub], qB0, z, 0, 0, 0);
      scB[sub] = __builtin_amdgcn_mfma_f32_16x16x32_bf16(k1[sub], qB1, sB, 0, 0, 0);
    }

    // ---- prefetch K(kt+1): window = softmax+PV (~600cy) covers L2 latency
    short8 nk0[4], nk1[4];
#pragma unroll
    for (int sub = 0; sub < 4; ++sub) {
      const unsigned short* kp = Kg + (size_t)ktn * 4096 + sub * 1024 + kO;
      nk0[sub] = *(const short8*)(kp);
      nk1[sub] = *(const short8*)(kp + 32);
    }

    // ---- softmax (log2 domain, defer-max)
    sm_step(scA, mA, lA, oA, kt == qt, qinA, quad);
    sm_step(scB, mB, lB, oB, kt == qt, qinB, quad);

    // ---- PV both streams (consume v0/v1; streams share V-frags)
    pv_reg(scA, oA, lP[0], v0, v1, l15, quad);
    pv_reg(scB, oB, lP[1], v0, v1, l15, quad);

    // ---- prefetch V(kt+1): window = next iter's QK+softmax
    short8 nv0[4], nv1[4];
#pragma unroll
    for (int n = 0; n < 4; ++n) {
      const unsigned short* vp = Vg + (size_t)n * 16 * 2048 + (size_t)ktn * 64 + vO;
      nv0[n] = *(const short8*)(vp);
      nv1[n] = *(const short8*)(vp + 32);
    }
#pragma unroll
    for (int i = 0; i < 4; ++i) {
      k0[i] = nk0[i]; k1[i] = nk1[i];
      v0[i] = nv0[i]; v1[i] = nv1[i];
    }
  }

  // ---- epilogue: per-lane 1/l, packed b64 stores for both streams
  int b = bh >> 4, hh = bh & 15;
  {
    float inv = 1.f / lA;
    int s = qt * 64 + h * 32 + l15;
    size_t orow = (size_t)(b * 2048 + s) * 1024 + hh * 64;
#pragma unroll
    for (int n = 0; n < 4; ++n) {
      uint2 ov;
      ov.x = pk2bf(oA[n][0] * inv, oA[n][1] * inv);
      ov.y = pk2bf(oA[n][2] * inv, oA[n][3] * inv);
      *(uint2*)(Oc + orow + n * 16 + quad * 4) = ov;
    }
  }
  {
    float inv = 1.f / lB;
    int s = qt * 64 + h * 32 + 16 + l15;
    size_t orow = (size_t)(b * 2048 + s) * 1024 + hh * 64;
#pragma unroll
    for (int n = 0; n < 4; ++n) {
      uint2 ov;
      ov.x = pk2bf(oB[n][0] * inv, oB[n][1] * inv);
      ov.y = pk2bf(oB[n][2] * inv, oB[n][3] * inv);
      *(uint2*)(Oc + orow + n * 16 + quad * 4) = ov;
    }
  }
}

// ---------------------------------------------------------------------------
extern "C" void kernel_launch(void* const* d_in, const int* in_sizes, int n_in,
                              void* d_out, int out_size, void* d_ws, size_t ws_size,
                              hipStream_t stream) {
  const float* x  = (const float*)d_in[0];
  const int* tokpos = (const int*)d_in[1];
  const float* Wq = (const float*)d_in[2];
  const float* Wk = (const float*)d_in[3];
  const float* Wv = (const float*)d_in[4];
  const float* Wo = (const float*)d_in[5];
  float* out = (float*)d_out;

  float* ws = (float*)d_ws;
  float* ctab = ws;
  float* stab = ctab + 65536;
  unsigned short* u = (unsigned short*)(stab + 65536);
  unsigned short* Qb  = u;
  unsigned short* Kb  = Qb + 4194304;
  unsigned short* Vb  = Kb + 4194304;   // transposed [bh][d][s]
  unsigned short* Oc  = Vb + 4194304;
  unsigned short* xb  = Oc + 4194304;
  unsigned short* Wqb = xb + 4194304;
  unsigned short* Wkb = Wqb + 1048576;
  unsigned short* Wvb = Wkb + 1048576;
  unsigned short* Wob = Wvb + 1048576;

  cvt_all<<<dim3(4096, 6), 256, 0, stream>>>(
      (const float4*)x, (const float4*)Wq, (const float4*)Wk,
      (const float4*)Wv, (const float4*)Wo,
      (ushort4*)xb, (ushort4*)Wqb, (ushort4*)Wkb, (ushort4*)Wvb, (ushort4*)Wob,
      tokpos, ctab, stab);

  qkv_mfma<<<dim3(64, 8, 3), 256, 0, stream>>>(
      xb, Wqb, Wkb, Wvb, ctab, stab, Qb, Kb, Vb);
  attn_flash<<<dim3(2048), 64, 0, stream>>>(Qb, Kb, Vb, Oc);
  oproj_mfma<<<dim3(64, 8), 256, 0, stream>>>(Oc, Wob, out);
}

// Round 10
// 180.968 us; speedup vs baseline: 1.1677x; 1.1677x over previous
//
#include <hip/hip_runtime.h>
#include <hip/hip_bf16.h>

// B=2, S=2048, D=1024, H=16, DK=64, THETA=10000
// Inputs fp32 (positions int32): x[2,2048,1024], token_positions[2048],
// Wq,Wk,Wv,Wo [1024,1024].  Output fp32 [2,2048,1024].
// proj: y[b,s,o] = sum_d x[b,s,d] * W[o,d]
//
// R20 = restore of R8's measured-best configuration (180.97us run; every
// component at session-best per-kernel time):
//   qkv R17:  64x128 depth-2 counted-vmcnt DMA pipeline + XCD panel clustering
//   oproj R17: same structure
//   attn R18: 2-wave half-tile dual-stream, LDS dbuf K/V, single raw
//             barrier/iter, defer-max
// R9 lesson (attn R19, 77us): register-direct K/V fragments double per-wave
// L2 traffic (no sharing) and expose chained load latency at ~1.4 waves/SIMD.
// LDS staging + counted-vmcnt pipelining wins whenever sharing exists
// (2nd confirmation; R7's B-direct was the 1st).

typedef __attribute__((ext_vector_type(8))) short short8;   // 8 bf16 = 4 VGPRs
typedef __attribute__((ext_vector_type(4))) float floatx4;  // MFMA accumulator

static __device__ __forceinline__ unsigned short f2bf(float f) {
  __hip_bfloat16 h = __float2bfloat16(f);
  return *(unsigned short*)&h;
}

// pack 2 floats -> 2 bf16 in one u32 (half-up rounding + v_perm byte pick).
// low ushort = bf16(a), high ushort = bf16(b). Finite inputs only.
static __device__ __forceinline__ unsigned int pk2bf(float a, float b) {
  unsigned int ua = __float_as_uint(a) + 0x8000u;
  unsigned int ub = __float_as_uint(b) + 0x8000u;
  return __builtin_amdgcn_perm(ub, ua, 0x07060302u);
}

// raw v_exp_f32 (2^x), single VALU transcendental; s_nop covers the
// trans->VALU dependency wait state.
static __device__ __forceinline__ float fexp2(float x) {
  float r;
  asm("v_exp_f32 %0, %1\n\ts_nop 0" : "=v"(r) : "v"(x));
  return r;
}

// async global->LDS DMA, 16 B per lane; lds base must be wave-uniform,
// HW writes lane i at ldsbase + i*16.
static __device__ __forceinline__ void gl2lds16(const unsigned short* g,
                                                unsigned short* l) {
  __builtin_amdgcn_global_load_lds(
      (const __attribute__((address_space(1))) void*)g,
      (__attribute__((address_space(3))) void*)l, 16, 0, 0);
}

// ---------------------------------------------------------------------------
// fp32 -> bf16 conversion for all 5 tensors + RoPE table gen, one launch.
// blockIdx.y: 0=x 1=Wq 2=Wk 3=Wv 4=Wo 5=rope tables
// ---------------------------------------------------------------------------
__global__ __launch_bounds__(256) void cvt_all(
    const float4* __restrict__ x,  const float4* __restrict__ wq,
    const float4* __restrict__ wk, const float4* __restrict__ wv,
    const float4* __restrict__ wo,
    ushort4* __restrict__ xb,  ushort4* __restrict__ wqb,
    ushort4* __restrict__ wkb, ushort4* __restrict__ wvb,
    ushort4* __restrict__ wob,
    const int* __restrict__ tokpos,
    float* __restrict__ ctab, float* __restrict__ stab) {
  int t = blockIdx.y;
  int i = blockIdx.x * 256 + threadIdx.x;
  if (t == 5) {
    if (i < 65536) {     // 2048 positions x 32 pair-freqs
      int s = i >> 5, f = i & 31;
      float inv = expf(-9.210340371976184f * (float)(2 * f) / 64.0f);
      float ang = (float)tokpos[s] * inv;
      ctab[i] = cosf(ang);
      stab[i] = sinf(ang);
    }
    return;
  }
  const float4* s = (t == 0) ? x : (t == 1) ? wq : (t == 2) ? wk : (t == 3) ? wv : wo;
  ushort4* d = (t == 0) ? xb : (t == 1) ? wqb : (t == 2) ? wkb : (t == 3) ? wvb : wob;
  int n4 = (t == 0) ? 1048576 : 262144;
  if (i < n4) {
    float4 v = s[i];
    ushort4 o;
    o.x = f2bf(v.x); o.y = f2bf(v.y); o.z = f2bf(v.z); o.w = f2bf(v.w);
    d[i] = o;
  }
}

// ---------------------------------------------------------------------------
// QKV projection R17: 64x128 tiles, depth-2 counted-vmcnt DMA pipeline +
// XCD panel clustering (t = bx + 64*by; XCD = t%8 = logical n-panel; each
// XCD serves ONE 128-col W panel per matrix -> W L2-resident).  Measured
// R8: qkv left top-5 (<46.3us).
// Pipeline per K-step (6 DMA loads/thread/tile):
//   compute(slot kt&1); s_barrier(A); issue L(kt+2)->slot kt&1;
//   s_waitcnt vmcnt(6) [retires L(kt+1) only]; s_barrier(B)
// LDS 48KB -> 3 blocks/CU; grid 64x8x3 = 1536 = 2 uniform rounds.
// Q pre-scaled by (1/sqrt(64))*log2(e); Q,K [bh][s][64]; V^T [bh][d][2048].
// ---------------------------------------------------------------------------
__global__ __launch_bounds__(256) void qkv_mfma(
    const unsigned short* __restrict__ X,
    const unsigned short* __restrict__ Wq,
    const unsigned short* __restrict__ Wk,
    const unsigned short* __restrict__ Wv,
    const float* __restrict__ ctab, const float* __restrict__ stab,
    unsigned short* __restrict__ Qo, unsigned short* __restrict__ Ko,
    unsigned short* __restrict__ Vo) {
  int mat = blockIdx.z;  // 0=q 1=k 2=v
  const unsigned short* W = (mat == 0) ? Wq : ((mat == 1) ? Wk : Wv);
  unsigned short* Out = (mat == 0) ? Qo : ((mat == 1) ? Ko : Vo);
  int t = blockIdx.x + (blockIdx.y << 6);   // 0..511
  int m0 = (t >> 3) * 64, n0 = (t & 7) * 128;

  __shared__ __align__(16) unsigned short lA[2][64 * 64];
  __shared__ __align__(16) unsigned short lB[2][128 * 64];
  int tid = threadIdx.x;
  int wave = tid >> 6, lane = tid & 63;
  int l15 = lane & 15, quad = lane >> 4;
  int rsub = lane >> 3, sch = lane & 7;
  int fsw = l15 & 7;

  floatx4 acc[4][2];
#pragma unroll
  for (int m = 0; m < 4; ++m)
#pragma unroll
    for (int n = 0; n < 2; ++n) acc[m][n] = (floatx4){0.f, 0.f, 0.f, 0.f};

  // prologue: L(0)->slot0 (6 loads), L(1)->slot1 (6 loads)
#pragma unroll
  for (int kp = 0; kp < 2; ++kp) {
#pragma unroll
    for (int p = 0; p < 2; ++p) {
      int r = wave * 16 + p * 8 + rsub;
      int g = sch ^ (r & 7);
      gl2lds16(X + (size_t)(m0 + r) * 1024 + kp * 64 + g * 8,
               lA[kp] + (wave * 16 + p * 8) * 64);
    }
#pragma unroll
    for (int p = 0; p < 4; ++p) {
      int r = wave * 32 + p * 8 + rsub;
      int g = sch ^ (r & 7);
      gl2lds16(W + (size_t)(n0 + r) * 1024 + kp * 64 + g * 8,
               lB[kp] + (wave * 32 + p * 8) * 64);
    }
  }
  asm volatile("s_waitcnt vmcnt(6)" ::: "memory");  // L(0) done
  __builtin_amdgcn_s_barrier();

  for (int kt = 0; kt < 16; ++kt) {
    int cur = kt & 1;
#pragma unroll
    for (int ks = 0; ks < 2; ++ks) {
      int slot = ((ks * 4 + quad) ^ fsw) * 8;
      short8 af[4], bf[2];
#pragma unroll
      for (int m = 0; m < 4; ++m)
        af[m] = *(const short8*)(lA[cur] + (m * 16 + l15) * 64 + slot);
#pragma unroll
      for (int n = 0; n < 2; ++n)
        bf[n] = *(const short8*)(lB[cur] + (wave * 32 + n * 16 + l15) * 64 + slot);
#pragma unroll
      for (int m = 0; m < 4; ++m)
#pragma unroll
        for (int n = 0; n < 2; ++n)
          acc[m][n] = __builtin_amdgcn_mfma_f32_16x16x32_bf16(
              af[m], bf[n], acc[m][n], 0, 0, 0);
    }
    if (kt == 15) break;
    __builtin_amdgcn_s_barrier();  // (A)
    if (kt < 14) {
#pragma unroll
      for (int p = 0; p < 2; ++p) {
        int r = wave * 16 + p * 8 + rsub;
        int g = sch ^ (r & 7);
        gl2lds16(X + (size_t)(m0 + r) * 1024 + (kt + 2) * 64 + g * 8,
                 lA[cur] + (wave * 16 + p * 8) * 64);
      }
#pragma unroll
      for (int p = 0; p < 4; ++p) {
        int r = wave * 32 + p * 8 + rsub;
        int g = sch ^ (r & 7);
        gl2lds16(W + (size_t)(n0 + r) * 1024 + (kt + 2) * 64 + g * 8,
                 lB[cur] + (wave * 32 + p * 8) * 64);
      }
      asm volatile("s_waitcnt vmcnt(6)" ::: "memory");  // L(kt+1) done
    } else {
      asm volatile("s_waitcnt vmcnt(0)" ::: "memory");  // drain L(15)
    }
    __builtin_amdgcn_s_barrier();  // (B)
  }

  // ---- fused RoPE / transpose epilogue (wave owns 32 cols, 64 rows)
#pragma unroll
  for (int n = 0; n < 2; ++n) {
    int col = n0 + wave * 32 + n * 16 + l15;  // 0..1023
    int h = col >> 6;
    int d = col & 63;
    int pi = d >> 1;
    bool odd = (d & 1) != 0;
    size_t hb = (size_t)h * 2048 * 64;
#pragma unroll
    for (int m = 0; m < 4; ++m) {
      int row0 = m0 + m * 16 + quad * 4;  // rows row0..row0+3
      int b = row0 >> 11;
      int s0 = row0 & 2047;
      size_t base = (size_t)b * 16 * 2048 * 64 + hb;
      if (mat == 2) {
        // V: packed b64 store along s (transposed layout [d][s])
        ushort4 pv;
        pv.x = f2bf(acc[m][n][0]);
        pv.y = f2bf(acc[m][n][1]);
        pv.z = f2bf(acc[m][n][2]);
        pv.w = f2bf(acc[m][n][3]);
        *(ushort4*)(Out + base + (size_t)d * 2048 + s0) = pv;
      } else {
#pragma unroll
        for (int i = 0; i < 4; ++i) {
          int s = s0 + i;
          float v = acc[m][n][i];
          float p = __shfl_xor(v, 1);
          float c = ctab[s * 32 + pi];
          float sn = stab[s * 32 + pi];
          float res = odd ? fmaf(p, sn, v * c) : fmaf(v, c, -p * sn);
          if (mat == 0) res *= 0.1803368801111204f;  // 0.125 * log2(e)
          Out[base + (size_t)s * 64 + d] = f2bf(res);
        }
      }
    }
  }
}

// ---------------------------------------------------------------------------
// Output projection R17: out = Oc @ Wo^T.  64x128 tiles, depth-2 pipeline,
// XCD panel clustering (Wo panel 256KB L2-resident per XCD).  fp32 store.
// ---------------------------------------------------------------------------
__global__ __launch_bounds__(256) void oproj_mfma(
    const unsigned short* __restrict__ A, const unsigned short* __restrict__ Wo,
    float* __restrict__ Out) {
  __shared__ __align__(16) unsigned short lA[2][64 * 64];
  __shared__ __align__(16) unsigned short lB[2][128 * 64];
  int tid = threadIdx.x;
  int wave = tid >> 6, lane = tid & 63;
  int l15 = lane & 15, quad = lane >> 4;
  int rsub = lane >> 3, sch = lane & 7;
  int fsw = l15 & 7;
  int t = blockIdx.x + (blockIdx.y << 6);   // 0..511
  int m0 = (t >> 3) * 64, n0 = (t & 7) * 128;

  floatx4 acc[4][2];
#pragma unroll
  for (int m = 0; m < 4; ++m)
#pragma unroll
    for (int n = 0; n < 2; ++n) acc[m][n] = (floatx4){0.f, 0.f, 0.f, 0.f};

#pragma unroll
  for (int kp = 0; kp < 2; ++kp) {
#pragma unroll
    for (int p = 0; p < 2; ++p) {
      int r = wave * 16 + p * 8 + rsub;
      int g = sch ^ (r & 7);
      gl2lds16(A + (size_t)(m0 + r) * 1024 + kp * 64 + g * 8,
               lA[kp] + (wave * 16 + p * 8) * 64);
    }
#pragma unroll
    for (int p = 0; p < 4; ++p) {
      int r = wave * 32 + p * 8 + rsub;
      int g = sch ^ (r & 7);
      gl2lds16(Wo + (size_t)(n0 + r) * 1024 + kp * 64 + g * 8,
               lB[kp] + (wave * 32 + p * 8) * 64);
    }
  }
  asm volatile("s_waitcnt vmcnt(6)" ::: "memory");  // L(0) done
  __builtin_amdgcn_s_barrier();

  for (int kt = 0; kt < 16; ++kt) {
    int cur = kt & 1;
#pragma unroll
    for (int ks = 0; ks < 2; ++ks) {
      int slot = ((ks * 4 + quad) ^ fsw) * 8;
      short8 af[4], bf[2];
#pragma unroll
      for (int m = 0; m < 4; ++m)
        af[m] = *(const short8*)(lA[cur] + (m * 16 + l15) * 64 + slot);
#pragma unroll
      for (int n = 0; n < 2; ++n)
        bf[n] = *(const short8*)(lB[cur] + (wave * 32 + n * 16 + l15) * 64 + slot);
#pragma unroll
      for (int m = 0; m < 4; ++m)
#pragma unroll
        for (int n = 0; n < 2; ++n)
          acc[m][n] = __builtin_amdgcn_mfma_f32_16x16x32_bf16(
              af[m], bf[n], acc[m][n], 0, 0, 0);
    }
    if (kt == 15) break;
    __builtin_amdgcn_s_barrier();  // (A)
    if (kt < 14) {
#pragma unroll
      for (int p = 0; p < 2; ++p) {
        int r = wave * 16 + p * 8 + rsub;
        int g = sch ^ (r & 7);
        gl2lds16(A + (size_t)(m0 + r) * 1024 + (kt + 2) * 64 + g * 8,
                 lA[cur] + (wave * 16 + p * 8) * 64);
      }
#pragma unroll
      for (int p = 0; p < 4; ++p) {
        int r = wave * 32 + p * 8 + rsub;
        int g = sch ^ (r & 7);
        gl2lds16(Wo + (size_t)(n0 + r) * 1024 + (kt + 2) * 64 + g * 8,
                 lB[cur] + (wave * 32 + p * 8) * 64);
      }
      asm volatile("s_waitcnt vmcnt(6)" ::: "memory");  // L(kt+1) done
    } else {
      asm volatile("s_waitcnt vmcnt(0)" ::: "memory");  // drain L(15)
    }
    __builtin_amdgcn_s_barrier();  // (B)
  }

#pragma unroll
  for (int m = 0; m < 4; ++m) {
#pragma unroll
    for (int n = 0; n < 2; ++n) {
      int col = n0 + wave * 32 + n * 16 + l15;
#pragma unroll
      for (int i = 0; i < 4; ++i) {
        int row = m0 + m * 16 + quad * 4 + i;
        Out[(size_t)row * 1024 + col] = acc[m][n][i];
      }
    }
  }
}

// ---------------------------------------------------------------------------
// Flash attention R18 (restored; 46.5us measured, session-best attn):
// half-tile dual-stream blocks, single raw barrier/iter, defer-max.
// 1024 blocks x 128 thr (2 waves); K/V double-buffered in LDS; one raw
// s_barrier per iter (lgkmcnt(0) only -- vmcnt NOT drained, so the kt+2
// register-prefetch loads fly across with a full compute phase in flight).
// Dual q-tile streams (pair x, 31-x) share staged kv-tiles; XCD-clustered
// decode keeps each bh's 512KB K/V in one XCD L2 (FETCH 62.6->12.3MB).
// ---------------------------------------------------------------------------
static __device__ __forceinline__ void qk_step(
    const unsigned short* lK, int l15, int c0, int c1,
    short8 q0, short8 q1, floatx4 (&sc)[4]) {
#pragma unroll
  for (int sub = 0; sub < 4; ++sub) {
    const unsigned short* kr = lK + (sub * 16 + l15) * 64;
    short8 a0 = *(const short8*)(kr + c0);
    short8 a1 = *(const short8*)(kr + c1);
    floatx4 s = {0.f, 0.f, 0.f, 0.f};
    s = __builtin_amdgcn_mfma_f32_16x16x32_bf16(a0, q0, s, 0, 0, 0);
    s = __builtin_amdgcn_mfma_f32_16x16x32_bf16(a1, q1, s, 0, 0, 0);
    sc[sub] = s;
  }
}

static __device__ __forceinline__ void sm_step(
    floatx4 (&sc)[4], float& m_i, float& l_i, floatx4 (&o)[4],
    bool diag, int qin, int quad) {
  if (diag) {  // causal mask on diagonal tile: k-within > q-within
#pragma unroll
    for (int sub = 0; sub < 4; ++sub)
#pragma unroll
      for (int i = 0; i < 4; ++i)
        if (sub * 16 + quad * 4 + i > qin) sc[sub][i] = -1e30f;
  }
  float mb = sc[0][0];
#pragma unroll
  for (int sub = 0; sub < 4; ++sub)
#pragma unroll
    for (int i = 0; i < 4; ++i) mb = fmaxf(mb, sc[sub][i]);
  mb = fmaxf(mb, __shfl_xor(mb, 16));
  mb = fmaxf(mb, __shfl_xor(mb, 32));

  // T13 defer-max: rescale only when some lane's max grew by > 8 (log2
  // domain, P <= 2^8; fp32 l/o headroom ample; normalized at epilogue).
  if (!__all(mb <= m_i + 8.f)) {
    float mn = fmaxf(m_i, mb);
    float al = fexp2(m_i - mn);
    m_i = mn;
    l_i *= al;
#pragma unroll
    for (int n = 0; n < 4; ++n) {
      o[n][0] *= al; o[n][1] *= al; o[n][2] *= al; o[n][3] *= al;
    }
  }
  float rs = 0.f;
#pragma unroll
  for (int sub = 0; sub < 4; ++sub)
#pragma unroll
    for (int i = 0; i < 4; ++i) {
      float p = fexp2(sc[sub][i] - m_i);
      sc[sub][i] = p;
      rs += p;
    }
  rs += __shfl_xor(rs, 16);
  rs += __shfl_xor(rs, 32);
  l_i += rs;
}

// P^T staging through XOR-swizzled lP row (q=l15), then PV MFMA.
// Write: k = sub*16+quad*4+i -> 16B slot sub*2+(quad>>1), 8B half quad&1,
// stored at slot^(l15&7).  Read: pa0 = k[quad*8..+8) -> slot quad^(l15&7);
// pa1 = k[32+quad*8..+8) -> slot (4+quad)^(l15&7).  Same-wave DS ordering
// makes the write->read turnaround barrier-free.
static __device__ __forceinline__ void pv_step(
    const floatx4 (&sc)[4], floatx4 (&o)[4], unsigned short* lPws,
    const unsigned short* lV, int l15, int quad, int c0, int c1) {
  int swz = l15 & 7;
  unsigned short* pw = lPws + l15 * 64;
#pragma unroll
  for (int sub = 0; sub < 4; ++sub) {
    uint2 w;
    w.x = pk2bf(sc[sub][0], sc[sub][1]);
    w.y = pk2bf(sc[sub][2], sc[sub][3]);
    int slot = (sub * 2 + (quad >> 1)) ^ swz;
    *(uint2*)(pw + slot * 8 + (quad & 1) * 4) = w;
  }
  short8 pa0 = *(const short8*)(pw + ((quad ^ swz) * 8));
  short8 pa1 = *(const short8*)(pw + (((4 + quad) ^ swz) * 8));
#pragma unroll
  for (int n = 0; n < 4; ++n) {
    const unsigned short* vr = lV + (n * 16 + l15) * 64;
    short8 vb0 = *(const short8*)(vr + c0);
    short8 vb1 = *(const short8*)(vr + c1);
    o[n] = __builtin_amdgcn_mfma_f32_16x16x32_bf16(vb0, pa0, o[n], 0, 0, 0);
    o[n] = __builtin_amdgcn_mfma_f32_16x16x32_bf16(vb1, pa1, o[n], 0, 0, 0);
  }
}

__global__ __launch_bounds__(128, 2) void attn_flash(
    const unsigned short* __restrict__ Q, const unsigned short* __restrict__ K,
    const unsigned short* __restrict__ Vt, unsigned short* __restrict__ Oc) {
  __shared__ __align__(16) unsigned short lK[2][64 * 64];  // [kj][d] swizzled
  __shared__ __align__(16) unsigned short lV[2][64 * 64];  // [d][kj] swizzled
  __shared__ __align__(16) unsigned short lP[4][16 * 64];  // [wave*2+stream]

  int tid = threadIdx.x;
  int wave = tid >> 6, lane = tid & 63;
  int l15 = lane & 15, quad = lane >> 4;

  // decode: id%8 = XCD = bh>>2; then bh-sub, then (pair, half)
  int id = blockIdx.x;                 // 0..1023
  int bh = (id & 7) * 4 + ((id >> 3) & 3);
  int rem = id >> 5;                   // 0..31
  int pair = rem >> 1;                 // 0..15
  int h = rem & 1;                     // which 32-row half of each tile
  int tA = pair, tB = 31 - pair;
  int NT = tB + 1;                     // kv tiles this block (17..32)

  size_t base = (size_t)bh * 2048 * 64;
  int qoff = h * 32 + wave * 16 + l15;   // q row within tile (0..63)

  // Q fragments (B-operand, loop-invariant) for both streams
  const unsigned short* qrowA = Q + base + (size_t)(tA * 64 + qoff) * 64;
  const unsigned short* qrowB = Q + base + (size_t)(tB * 64 + qoff) * 64;
  short8 qA0 = *(const short8*)(qrowA + quad * 8);
  short8 qA1 = *(const short8*)(qrowA + 32 + quad * 8);
  short8 qB0 = *(const short8*)(qrowB + quad * 8);
  short8 qB1 = *(const short8*)(qrowB + 32 + quad * 8);

  floatx4 oA[4], oB[4];
  float mA_i = -1e30f, lA_i = 0.f, mB_i = -1e30f, lB_i = 0.f;
#pragma unroll
  for (int n = 0; n < 4; ++n) {
    oA[n] = (floatx4){0.f, 0.f, 0.f, 0.f};
    oB[n] = (floatx4){0.f, 0.f, 0.f, 0.f};
  }

  // staging: 128 threads cover 64 rows x 8 chunks; this thread owns rows
  // r0+{0,16,32,48} (same &7 -> same swizzled slot sl), 16B chunk g.
  int r0 = tid >> 3, g = tid & 7;      // r0 0..15
  int e0 = g * 8;                      // global element offset of chunk g
  int sl = (g ^ (r0 & 7)) * 8;         // swizzled LDS slot (element offset)
  int fsw = l15 & 7;                   // fragment-read swizzle
  int c0 = (quad ^ fsw) * 8;           // slot of global chunk quad
  int c1 = ((quad + 4) ^ fsw) * 8;     // slot of global chunk quad+4

  short8 pk0, pk1, pk2, pk3, pv0, pv1, pv2, pv3;

  // prologue: load kt=0, write buf0, issue loads kt=1 (fly across barrier)
  {
    const unsigned short* kp = K + base;
    const unsigned short* vp = Vt + base;
    pk0 = *(const short8*)(kp + (r0 +  0) * 64 + e0);
    pk1 = *(const short8*)(kp + (r0 + 16) * 64 + e0);
    pk2 = *(const short8*)(kp + (r0 + 32) * 64 + e0);
    pk3 = *(const short8*)(kp + (r0 + 48) * 64 + e0);
    pv0 = *(const short8*)(vp + (size_t)(r0 +  0) * 2048 + e0);
    pv1 = *(const short8*)(vp + (size_t)(r0 + 16) * 2048 + e0);
    pv2 = *(const short8*)(vp + (size_t)(r0 + 32) * 2048 + e0);
    pv3 = *(const short8*)(vp + (size_t)(r0 + 48) * 2048 + e0);
  }
  *(short8*)(lK[0] + (r0 +  0) * 64 + sl) = pk0;
  *(short8*)(lK[0] + (r0 + 16) * 64 + sl) = pk1;
  *(short8*)(lK[0] + (r0 + 32) * 64 + sl) = pk2;
  *(short8*)(lK[0] + (r0 + 48) * 64 + sl) = pk3;
  *(short8*)(lV[0] + (r0 +  0) * 64 + sl) = pv0;
  *(short8*)(lV[0] + (r0 + 16) * 64 + sl) = pv1;
  *(short8*)(lV[0] + (r0 + 32) * 64 + sl) = pv2;
  *(short8*)(lV[0] + (r0 + 48) * 64 + sl) = pv3;
  {  // NT >= 17, kt=1 always exists
    const unsigned short* kp = K + base + 4096;
    const unsigned short* vp = Vt + base + 64;
    pk0 = *(const short8*)(kp + (r0 +  0) * 64 + e0);
    pk1 = *(const short8*)(kp + (r0 + 16) * 64 + e0);
    pk2 = *(const short8*)(kp + (r0 + 32) * 64 + e0);
    pk3 = *(const short8*)(kp + (r0 + 48) * 64 + e0);
    pv0 = *(const short8*)(vp + (size_t)(r0 +  0) * 2048 + e0);
    pv1 = *(const short8*)(vp + (size_t)(r0 + 16) * 2048 + e0);
    pv2 = *(const short8*)(vp + (size_t)(r0 + 32) * 2048 + e0);
    pv3 = *(const short8*)(vp + (size_t)(r0 + 48) * 2048 + e0);
  }
  asm volatile("s_waitcnt lgkmcnt(0)" ::: "memory");
  __builtin_amdgcn_s_barrier();
  __builtin_amdgcn_sched_barrier(0);

  int qin = qoff;

  for (int kt = 0; kt < NT; ++kt) {
    int cur = kt & 1;
    bool aAct = (kt <= tA);
    const unsigned short* lKc = lK[cur];
    const unsigned short* lVc = lV[cur];

    // ---- dual-stream compute: B always, A while kt <= tA
    floatx4 scB[4], scA[4];
    qk_step(lKc, l15, c0, c1, qB0, qB1, scB);
    if (aAct) qk_step(lKc, l15, c0, c1, qA0, qA1, scA);

    sm_step(scB, mB_i, lB_i, oB, kt == NT - 1, qin, quad);
    if (aAct) sm_step(scA, mA_i, lA_i, oA, kt == tA, qin, quad);

    pv_step(scB, oB, lP[wave * 2], lVc, l15, quad, c0, c1);
    if (aAct) pv_step(scA, oA, lP[wave * 2 + 1], lVc, l15, quad, c0, c1);

    if (kt + 1 < NT) {
      // write next tile (regs hold kt+1 data) into the other buffer
      unsigned short* wK = lK[cur ^ 1];
      unsigned short* wV = lV[cur ^ 1];
      *(short8*)(wK + (r0 +  0) * 64 + sl) = pk0;
      *(short8*)(wK + (r0 + 16) * 64 + sl) = pk1;
      *(short8*)(wK + (r0 + 32) * 64 + sl) = pk2;
      *(short8*)(wK + (r0 + 48) * 64 + sl) = pk3;
      *(short8*)(wV + (r0 +  0) * 64 + sl) = pv0;
      *(short8*)(wV + (r0 + 16) * 64 + sl) = pv1;
      *(short8*)(wV + (r0 + 32) * 64 + sl) = pv2;
      *(short8*)(wV + (r0 + 48) * 64 + sl) = pv3;
      if (kt + 2 < NT) {  // issue loads for kt+2; consumed end of next iter
        const unsigned short* kp = K + base + (size_t)(kt + 2) * 4096;
        const unsigned short* vp = Vt + base + (size_t)(kt + 2) * 64;
        pk0 = *(const short8*)(kp + (r0 +  0) * 64 + e0);
        pk1 = *(const short8*)(kp + (r0 + 16) * 64 + e0);
        pk2 = *(const short8*)(kp + (r0 + 32) * 64 + e0);
        pk3 = *(const short8*)(kp + (r0 + 48) * 64 + e0);
        pv0 = *(const short8*)(vp + (size_t)(r0 +  0) * 2048 + e0);
        pv1 = *(const short8*)(vp + (size_t)(r0 + 16) * 2048 + e0);
        pv2 = *(const short8*)(vp + (size_t)(r0 + 32) * 2048 + e0);
        pv3 = *(const short8*)(vp + (size_t)(r0 + 48) * 2048 + e0);
      }
      // drain my ds reads+writes, then raw barrier (vmcnt NOT drained:
      // the kt+2 loads stay in flight across it)
      asm volatile("s_waitcnt lgkmcnt(0)" ::: "memory");
      __builtin_amdgcn_s_barrier();
      __builtin_amdgcn_sched_barrier(0);
    }
  }

  // ---- epilogue: per-lane 1/l, packed b64 stores for both streams
  int b = bh >> 4, hh = bh & 15;
  {
    float inv = 1.f / lB_i;
    int s = tB * 64 + qoff;
    size_t orow = (size_t)(b * 2048 + s) * 1024 + hh * 64;
#pragma unroll
    for (int n = 0; n < 4; ++n) {
      uint2 ov;
      ov.x = pk2bf(oB[n][0] * inv, oB[n][1] * inv);
      ov.y = pk2bf(oB[n][2] * inv, oB[n][3] * inv);
      *(uint2*)(Oc + orow + n * 16 + quad * 4) = ov;
    }
  }
  {
    float inv = 1.f / lA_i;
    int s = tA * 64 + qoff;
    size_t orow = (size_t)(b * 2048 + s) * 1024 + hh * 64;
#pragma unroll
    for (int n = 0; n < 4; ++n) {
      uint2 ov;
      ov.x = pk2bf(oA[n][0] * inv, oA[n][1] * inv);
      ov.y = pk2bf(oA[n][2] * inv, oA[n][3] * inv);
      *(uint2*)(Oc + orow + n * 16 + quad * 4) = ov;
    }
  }
}

// ---------------------------------------------------------------------------
extern "C" void kernel_launch(void* const* d_in, const int* in_sizes, int n_in,
                              void* d_out, int out_size, void* d_ws, size_t ws_size,
                              hipStream_t stream) {
  const float* x  = (const float*)d_in[0];
  const int* tokpos = (const int*)d_in[1];
  const float* Wq = (const float*)d_in[2];
  const float* Wk = (const float*)d_in[3];
  const float* Wv = (const float*)d_in[4];
  const float* Wo = (const float*)d_in[5];
  float* out = (float*)d_out;

  float* ws = (float*)d_ws;
  float* ctab = ws;
  float* stab = ctab + 65536;
  unsigned short* u = (unsigned short*)(stab + 65536);
  unsigned short* Qb  = u;
  unsigned short* Kb  = Qb + 4194304;
  unsigned short* Vb  = Kb + 4194304;   // transposed [bh][d][s]
  unsigned short* Oc  = Vb + 4194304;
  unsigned short* xb  = Oc + 4194304;
  unsigned short* Wqb = xb + 4194304;
  unsigned short* Wkb = Wqb + 1048576;
  unsigned short* Wvb = Wkb + 1048576;
  unsigned short* Wob = Wvb + 1048576;

  cvt_all<<<dim3(4096, 6), 256, 0, stream>>>(
      (const float4*)x, (const float4*)Wq, (const float4*)Wk,
      (const float4*)Wv, (const float4*)Wo,
      (ushort4*)xb, (ushort4*)Wqb, (ushort4*)Wkb, (ushort4*)Wvb, (ushort4*)Wob,
      tokpos, ctab, stab);

  qkv_mfma<<<dim3(64, 8, 3), 256, 0, stream>>>(
      xb, Wqb, Wkb, Wvb, ctab, stab, Qb, Kb, Vb);
  attn_flash<<<dim3(1024), 128, 0, stream>>>(Qb, Kb, Vb, Oc);
  oproj_mfma<<<dim3(64, 8), 256, 0, stream>>>(Oc, Wob, out);
}

// Round 11
// 179.845 us; speedup vs baseline: 1.1750x; 1.0062x over previous
//
#include <hip/hip_runtime.h>
#include <hip/hip_bf16.h>

// B=2, S=2048, D=1024, H=16, DK=64, THETA=10000
// R21 = R10 config (measured 180.97, reproducible) with attn moved to a
// 4-wave full-tile dual-stream block: LDS 48KB -> 3 blocks/CU = 12 waves/CU
// (3/SIMD, +50% TLP vs the 2-wave version's 2/SIMD) while keeping the
// verified R14 sync scheme (dbuf K/V, single raw barrier + lgkmcnt(0) per
// iter, vmcnt never drained mid-loop) and defer-max.  Softmax max/sum
// reductions rewritten as explicit trees (serial 16-chain -> depth-4).

typedef __attribute__((ext_vector_type(8))) short short8;   // 8 bf16 = 4 VGPRs
typedef __attribute__((ext_vector_type(4))) float floatx4;  // MFMA accumulator

static __device__ __forceinline__ unsigned short f2bf(float f) {
  __hip_bfloat16 h = __float2bfloat16(f);
  return *(unsigned short*)&h;
}

// pack 2 floats -> 2 bf16 in one u32 (half-up rounding + v_perm byte pick).
static __device__ __forceinline__ unsigned int pk2bf(float a, float b) {
  unsigned int ua = __float_as_uint(a) + 0x8000u;
  unsigned int ub = __float_as_uint(b) + 0x8000u;
  return __builtin_amdgcn_perm(ub, ua, 0x07060302u);
}

// raw v_exp_f32 (2^x), single VALU transcendental.
static __device__ __forceinline__ float fexp2(float x) {
  float r;
  asm("v_exp_f32 %0, %1\n\ts_nop 0" : "=v"(r) : "v"(x));
  return r;
}

// async global->LDS DMA, 16 B per lane.
static __device__ __forceinline__ void gl2lds16(const unsigned short* g,
                                                unsigned short* l) {
  __builtin_amdgcn_global_load_lds(
      (const __attribute__((address_space(1))) void*)g,
      (__attribute__((address_space(3))) void*)l, 16, 0, 0);
}

// ---------------------------------------------------------------------------
// fp32 -> bf16 conversion for all 5 tensors + RoPE table gen, one launch.
// ---------------------------------------------------------------------------
__global__ __launch_bounds__(256) void cvt_all(
    const float4* __restrict__ x,  const float4* __restrict__ wq,
    const float4* __restrict__ wk, const float4* __restrict__ wv,
    const float4* __restrict__ wo,
    ushort4* __restrict__ xb,  ushort4* __restrict__ wqb,
    ushort4* __restrict__ wkb, ushort4* __restrict__ wvb,
    ushort4* __restrict__ wob,
    const int* __restrict__ tokpos,
    float* __restrict__ ctab, float* __restrict__ stab) {
  int t = blockIdx.y;
  int i = blockIdx.x * 256 + threadIdx.x;
  if (t == 5) {
    if (i < 65536) {     // 2048 positions x 32 pair-freqs
      int s = i >> 5, f = i & 31;
      float inv = expf(-9.210340371976184f * (float)(2 * f) / 64.0f);
      float ang = (float)tokpos[s] * inv;
      ctab[i] = cosf(ang);
      stab[i] = sinf(ang);
    }
    return;
  }
  const float4* s = (t == 0) ? x : (t == 1) ? wq : (t == 2) ? wk : (t == 3) ? wv : wo;
  ushort4* d = (t == 0) ? xb : (t == 1) ? wqb : (t == 2) ? wkb : (t == 3) ? wvb : wob;
  int n4 = (t == 0) ? 1048576 : 262144;
  if (i < n4) {
    float4 v = s[i];
    ushort4 o;
    o.x = f2bf(v.x); o.y = f2bf(v.y); o.z = f2bf(v.z); o.w = f2bf(v.w);
    d[i] = o;
  }
}

// ---------------------------------------------------------------------------
// QKV projection R17 (unchanged, measured best): 64x128 tiles, depth-2
// counted-vmcnt DMA pipeline + XCD panel clustering (t = bx + 64*by;
// XCD = t%8 = logical n-panel -> 3x256KB W panels L2-resident per XCD).
// Q pre-scaled by (1/sqrt(64))*log2(e); Q,K [bh][s][64]; V^T [bh][d][2048].
// ---------------------------------------------------------------------------
__global__ __launch_bounds__(256) void qkv_mfma(
    const unsigned short* __restrict__ X,
    const unsigned short* __restrict__ Wq,
    const unsigned short* __restrict__ Wk,
    const unsigned short* __restrict__ Wv,
    const float* __restrict__ ctab, const float* __restrict__ stab,
    unsigned short* __restrict__ Qo, unsigned short* __restrict__ Ko,
    unsigned short* __restrict__ Vo) {
  int mat = blockIdx.z;  // 0=q 1=k 2=v
  const unsigned short* W = (mat == 0) ? Wq : ((mat == 1) ? Wk : Wv);
  unsigned short* Out = (mat == 0) ? Qo : ((mat == 1) ? Ko : Vo);
  int t = blockIdx.x + (blockIdx.y << 6);   // 0..511
  int m0 = (t >> 3) * 64, n0 = (t & 7) * 128;

  __shared__ __align__(16) unsigned short lA[2][64 * 64];
  __shared__ __align__(16) unsigned short lB[2][128 * 64];
  int tid = threadIdx.x;
  int wave = tid >> 6, lane = tid & 63;
  int l15 = lane & 15, quad = lane >> 4;
  int rsub = lane >> 3, sch = lane & 7;
  int fsw = l15 & 7;

  floatx4 acc[4][2];
#pragma unroll
  for (int m = 0; m < 4; ++m)
#pragma unroll
    for (int n = 0; n < 2; ++n) acc[m][n] = (floatx4){0.f, 0.f, 0.f, 0.f};

  // prologue: L(0)->slot0 (6 loads), L(1)->slot1 (6 loads)
#pragma unroll
  for (int kp = 0; kp < 2; ++kp) {
#pragma unroll
    for (int p = 0; p < 2; ++p) {
      int r = wave * 16 + p * 8 + rsub;
      int g = sch ^ (r & 7);
      gl2lds16(X + (size_t)(m0 + r) * 1024 + kp * 64 + g * 8,
               lA[kp] + (wave * 16 + p * 8) * 64);
    }
#pragma unroll
    for (int p = 0; p < 4; ++p) {
      int r = wave * 32 + p * 8 + rsub;
      int g = sch ^ (r & 7);
      gl2lds16(W + (size_t)(n0 + r) * 1024 + kp * 64 + g * 8,
               lB[kp] + (wave * 32 + p * 8) * 64);
    }
  }
  asm volatile("s_waitcnt vmcnt(6)" ::: "memory");  // L(0) done
  __builtin_amdgcn_s_barrier();

  for (int kt = 0; kt < 16; ++kt) {
    int cur = kt & 1;
#pragma unroll
    for (int ks = 0; ks < 2; ++ks) {
      int slot = ((ks * 4 + quad) ^ fsw) * 8;
      short8 af[4], bf[2];
#pragma unroll
      for (int m = 0; m < 4; ++m)
        af[m] = *(const short8*)(lA[cur] + (m * 16 + l15) * 64 + slot);
#pragma unroll
      for (int n = 0; n < 2; ++n)
        bf[n] = *(const short8*)(lB[cur] + (wave * 32 + n * 16 + l15) * 64 + slot);
#pragma unroll
      for (int m = 0; m < 4; ++m)
#pragma unroll
        for (int n = 0; n < 2; ++n)
          acc[m][n] = __builtin_amdgcn_mfma_f32_16x16x32_bf16(
              af[m], bf[n], acc[m][n], 0, 0, 0);
    }
    if (kt == 15) break;
    __builtin_amdgcn_s_barrier();  // (A)
    if (kt < 14) {
#pragma unroll
      for (int p = 0; p < 2; ++p) {
        int r = wave * 16 + p * 8 + rsub;
        int g = sch ^ (r & 7);
        gl2lds16(X + (size_t)(m0 + r) * 1024 + (kt + 2) * 64 + g * 8,
                 lA[cur] + (wave * 16 + p * 8) * 64);
      }
#pragma unroll
      for (int p = 0; p < 4; ++p) {
        int r = wave * 32 + p * 8 + rsub;
        int g = sch ^ (r & 7);
        gl2lds16(W + (size_t)(n0 + r) * 1024 + (kt + 2) * 64 + g * 8,
                 lB[cur] + (wave * 32 + p * 8) * 64);
      }
      asm volatile("s_waitcnt vmcnt(6)" ::: "memory");  // L(kt+1) done
    } else {
      asm volatile("s_waitcnt vmcnt(0)" ::: "memory");  // drain L(15)
    }
    __builtin_amdgcn_s_barrier();  // (B)
  }

  // ---- fused RoPE / transpose epilogue (wave owns 32 cols, 64 rows)
#pragma unroll
  for (int n = 0; n < 2; ++n) {
    int col = n0 + wave * 32 + n * 16 + l15;  // 0..1023
    int h = col >> 6;
    int d = col & 63;
    int pi = d >> 1;
    bool odd = (d & 1) != 0;
    size_t hb = (size_t)h * 2048 * 64;
#pragma unroll
    for (int m = 0; m < 4; ++m) {
      int row0 = m0 + m * 16 + quad * 4;  // rows row0..row0+3
      int b = row0 >> 11;
      int s0 = row0 & 2047;
      size_t base = (size_t)b * 16 * 2048 * 64 + hb;
      if (mat == 2) {
        // V: packed b64 store along s (transposed layout [d][s])
        ushort4 pv;
        pv.x = f2bf(acc[m][n][0]);
        pv.y = f2bf(acc[m][n][1]);
        pv.z = f2bf(acc[m][n][2]);
        pv.w = f2bf(acc[m][n][3]);
        *(ushort4*)(Out + base + (size_t)d * 2048 + s0) = pv;
      } else {
#pragma unroll
        for (int i = 0; i < 4; ++i) {
          int s = s0 + i;
          float v = acc[m][n][i];
          float p = __shfl_xor(v, 1);
          float c = ctab[s * 32 + pi];
          float sn = stab[s * 32 + pi];
          float res = odd ? fmaf(p, sn, v * c) : fmaf(v, c, -p * sn);
          if (mat == 0) res *= 0.1803368801111204f;  // 0.125 * log2(e)
          Out[base + (size_t)s * 64 + d] = f2bf(res);
        }
      }
    }
  }
}

// ---------------------------------------------------------------------------
// Output projection R17 (unchanged): 64x128 tiles, depth-2 pipeline,
// XCD panel clustering.  fp32 store.
// ---------------------------------------------------------------------------
__global__ __launch_bounds__(256) void oproj_mfma(
    const unsigned short* __restrict__ A, const unsigned short* __restrict__ Wo,
    float* __restrict__ Out) {
  __shared__ __align__(16) unsigned short lA[2][64 * 64];
  __shared__ __align__(16) unsigned short lB[2][128 * 64];
  int tid = threadIdx.x;
  int wave = tid >> 6, lane = tid & 63;
  int l15 = lane & 15, quad = lane >> 4;
  int rsub = lane >> 3, sch = lane & 7;
  int fsw = l15 & 7;
  int t = blockIdx.x + (blockIdx.y << 6);   // 0..511
  int m0 = (t >> 3) * 64, n0 = (t & 7) * 128;

  floatx4 acc[4][2];
#pragma unroll
  for (int m = 0; m < 4; ++m)
#pragma unroll
    for (int n = 0; n < 2; ++n) acc[m][n] = (floatx4){0.f, 0.f, 0.f, 0.f};

#pragma unroll
  for (int kp = 0; kp < 2; ++kp) {
#pragma unroll
    for (int p = 0; p < 2; ++p) {
      int r = wave * 16 + p * 8 + rsub;
      int g = sch ^ (r & 7);
      gl2lds16(A + (size_t)(m0 + r) * 1024 + kp * 64 + g * 8,
               lA[kp] + (wave * 16 + p * 8) * 64);
    }
#pragma unroll
    for (int p = 0; p < 4; ++p) {
      int r = wave * 32 + p * 8 + rsub;
      int g = sch ^ (r & 7);
      gl2lds16(Wo + (size_t)(n0 + r) * 1024 + kp * 64 + g * 8,
               lB[kp] + (wave * 32 + p * 8) * 64);
    }
  }
  asm volatile("s_waitcnt vmcnt(6)" ::: "memory");  // L(0) done
  __builtin_amdgcn_s_barrier();

  for (int kt = 0; kt < 16; ++kt) {
    int cur = kt & 1;
#pragma unroll
    for (int ks = 0; ks < 2; ++ks) {
      int slot = ((ks * 4 + quad) ^ fsw) * 8;
      short8 af[4], bf[2];
#pragma unroll
      for (int m = 0; m < 4; ++m)
        af[m] = *(const short8*)(lA[cur] + (m * 16 + l15) * 64 + slot);
#pragma unroll
      for (int n = 0; n < 2; ++n)
        bf[n] = *(const short8*)(lB[cur] + (wave * 32 + n * 16 + l15) * 64 + slot);
#pragma unroll
      for (int m = 0; m < 4; ++m)
#pragma unroll
        for (int n = 0; n < 2; ++n)
          acc[m][n] = __builtin_amdgcn_mfma_f32_16x16x32_bf16(
              af[m], bf[n], acc[m][n], 0, 0, 0);
    }
    if (kt == 15) break;
    __builtin_amdgcn_s_barrier();  // (A)
    if (kt < 14) {
#pragma unroll
      for (int p = 0; p < 2; ++p) {
        int r = wave * 16 + p * 8 + rsub;
        int g = sch ^ (r & 7);
        gl2lds16(A + (size_t)(m0 + r) * 1024 + (kt + 2) * 64 + g * 8,
                 lA[cur] + (wave * 16 + p * 8) * 64);
      }
#pragma unroll
      for (int p = 0; p < 4; ++p) {
        int r = wave * 32 + p * 8 + rsub;
        int g = sch ^ (r & 7);
        gl2lds16(Wo + (size_t)(n0 + r) * 1024 + (kt + 2) * 64 + g * 8,
                 lB[cur] + (wave * 32 + p * 8) * 64);
      }
      asm volatile("s_waitcnt vmcnt(6)" ::: "memory");  // L(kt+1) done
    } else {
      asm volatile("s_waitcnt vmcnt(0)" ::: "memory");  // drain L(15)
    }
    __builtin_amdgcn_s_barrier();  // (B)
  }

#pragma unroll
  for (int m = 0; m < 4; ++m) {
#pragma unroll
    for (int n = 0; n < 2; ++n) {
      int col = n0 + wave * 32 + n * 16 + l15;
#pragma unroll
      for (int i = 0; i < 4; ++i) {
        int row = m0 + m * 16 + quad * 4 + i;
        Out[(size_t)row * 1024 + col] = acc[m][n][i];
      }
    }
  }
}

// ---------------------------------------------------------------------------
// Flash attention R21: 4-wave full-tile dual-stream + R14 sync + defer-max.
// R10 diagnosis: both 4-wave(2 syncthreads) and 2-wave(raw barrier) measure
// 46.5us -> barrier WIDTH is not the lever; both had 2 waves/SIMD.  This
// config raises TLP: 512 blocks x 256 thr (4 waves, each 16 q-rows x 2
// streams); LDS = lK/lV dbuf 32KB + lP[8] 16KB = 48KB -> 3 blocks/CU =
// 12 waves/CU = 3 waves/SIMD (+50%).  Sync scheme verified in R5-R10:
// one raw s_barrier + lgkmcnt(0) per iter, vmcnt never drained in-loop
// (kt+2 register-prefetch loads fly across).  Softmax reductions as
// explicit trees (was a 16-long serial fmax/add chain; compiler cannot
// reassociate fmax without fast-math).
// ---------------------------------------------------------------------------
static __device__ __forceinline__ void qk_step(
    const unsigned short* lK, int l15, int c0, int c1,
    short8 q0, short8 q1, floatx4 (&sc)[4]) {
#pragma unroll
  for (int sub = 0; sub < 4; ++sub) {
    const unsigned short* kr = lK + (sub * 16 + l15) * 64;
    short8 a0 = *(const short8*)(kr + c0);
    short8 a1 = *(const short8*)(kr + c1);
    floatx4 s = {0.f, 0.f, 0.f, 0.f};
    s = __builtin_amdgcn_mfma_f32_16x16x32_bf16(a0, q0, s, 0, 0, 0);
    s = __builtin_amdgcn_mfma_f32_16x16x32_bf16(a1, q1, s, 0, 0, 0);
    sc[sub] = s;
  }
}

static __device__ __forceinline__ void sm_step(
    floatx4 (&sc)[4], float& m_i, float& l_i, floatx4 (&o)[4],
    bool diag, int qin, int quad) {
  if (diag) {  // causal mask on diagonal tile: k-within > q-within
#pragma unroll
    for (int sub = 0; sub < 4; ++sub)
#pragma unroll
      for (int i = 0; i < 4; ++i)
        if (sub * 16 + quad * 4 + i > qin) sc[sub][i] = -1e30f;
  }
  // tree max (depth 4, was serial 16-chain)
  float t0 = fmaxf(fmaxf(sc[0][0], sc[0][1]), fmaxf(sc[0][2], sc[0][3]));
  float t1 = fmaxf(fmaxf(sc[1][0], sc[1][1]), fmaxf(sc[1][2], sc[1][3]));
  float t2 = fmaxf(fmaxf(sc[2][0], sc[2][1]), fmaxf(sc[2][2], sc[2][3]));
  float t3 = fmaxf(fmaxf(sc[3][0], sc[3][1]), fmaxf(sc[3][2], sc[3][3]));
  float mb = fmaxf(fmaxf(t0, t1), fmaxf(t2, t3));
  mb = fmaxf(mb, __shfl_xor(mb, 16));
  mb = fmaxf(mb, __shfl_xor(mb, 32));

  // T13 defer-max: rescale only when some lane's max grew by > 8 (log2
  // domain, P <= 2^8; fp32 l/o headroom ample; normalized at epilogue).
  if (!__all(mb <= m_i + 8.f)) {
    float mn = fmaxf(m_i, mb);
    float al = fexp2(m_i - mn);
    m_i = mn;
    l_i *= al;
#pragma unroll
    for (int n = 0; n < 4; ++n) {
      o[n][0] *= al; o[n][1] *= al; o[n][2] *= al; o[n][3] *= al;
    }
  }
#pragma unroll
  for (int sub = 0; sub < 4; ++sub)
#pragma unroll
    for (int i = 0; i < 4; ++i)
      sc[sub][i] = fexp2(sc[sub][i] - m_i);
  // tree sum
  float s0 = (sc[0][0] + sc[0][1]) + (sc[0][2] + sc[0][3]);
  float s1 = (sc[1][0] + sc[1][1]) + (sc[1][2] + sc[1][3]);
  float s2 = (sc[2][0] + sc[2][1]) + (sc[2][2] + sc[2][3]);
  float s3 = (sc[3][0] + sc[3][1]) + (sc[3][2] + sc[3][3]);
  float rs = (s0 + s1) + (s2 + s3);
  rs += __shfl_xor(rs, 16);
  rs += __shfl_xor(rs, 32);
  l_i += rs;
}

// P^T staging through XOR-swizzled lP row (q=l15), then PV MFMA.
// Same-wave DS ordering makes the write->read turnaround barrier-free.
static __device__ __forceinline__ void pv_step(
    const floatx4 (&sc)[4], floatx4 (&o)[4], unsigned short* lPws,
    const unsigned short* lV, int l15, int quad, int c0, int c1) {
  int swz = l15 & 7;
  unsigned short* pw = lPws + l15 * 64;
#pragma unroll
  for (int sub = 0; sub < 4; ++sub) {
    uint2 w;
    w.x = pk2bf(sc[sub][0], sc[sub][1]);
    w.y = pk2bf(sc[sub][2], sc[sub][3]);
    int slot = (sub * 2 + (quad >> 1)) ^ swz;
    *(uint2*)(pw + slot * 8 + (quad & 1) * 4) = w;
  }
  short8 pa0 = *(const short8*)(pw + ((quad ^ swz) * 8));
  short8 pa1 = *(const short8*)(pw + (((4 + quad) ^ swz) * 8));
#pragma unroll
  for (int n = 0; n < 4; ++n) {
    const unsigned short* vr = lV + (n * 16 + l15) * 64;
    short8 vb0 = *(const short8*)(vr + c0);
    short8 vb1 = *(const short8*)(vr + c1);
    o[n] = __builtin_amdgcn_mfma_f32_16x16x32_bf16(vb0, pa0, o[n], 0, 0, 0);
    o[n] = __builtin_amdgcn_mfma_f32_16x16x32_bf16(vb1, pa1, o[n], 0, 0, 0);
  }
}

__global__ __launch_bounds__(256, 3) void attn_flash(
    const unsigned short* __restrict__ Q, const unsigned short* __restrict__ K,
    const unsigned short* __restrict__ Vt, unsigned short* __restrict__ Oc) {
  __shared__ __align__(16) unsigned short lK[2][64 * 64];  // [kj][d] swizzled
  __shared__ __align__(16) unsigned short lV[2][64 * 64];  // [d][kj] swizzled
  __shared__ __align__(16) unsigned short lP[8][16 * 64];  // [wave*2+stream]

  int tid = threadIdx.x;
  int wave = tid >> 6, lane = tid & 63;
  int l15 = lane & 15, quad = lane >> 4;

  // decode: id%8 = XCD = bh>>2; then bh-sub, then pair
  int id = blockIdx.x;                 // 0..511
  int bh = (id & 7) * 4 + ((id >> 3) & 3);
  int pair = id >> 5;                  // 0..15
  int tA = pair, tB = 31 - pair;
  int NT = tB + 1;                     // kv tiles this block (17..32)

  size_t base = (size_t)bh * 2048 * 64;
  int qoff = wave * 16 + l15;          // q row within tile (0..63)

  // Q fragments (B-operand, loop-invariant) for both streams
  const unsigned short* qrowA = Q + base + (size_t)(tA * 64 + qoff) * 64;
  const unsigned short* qrowB = Q + base + (size_t)(tB * 64 + qoff) * 64;
  short8 qA0 = *(const short8*)(qrowA + quad * 8);
  short8 qA1 = *(const short8*)(qrowA + 32 + quad * 8);
  short8 qB0 = *(const short8*)(qrowB + quad * 8);
  short8 qB1 = *(const short8*)(qrowB + 32 + quad * 8);

  floatx4 oA[4], oB[4];
  float mA_i = -1e30f, lA_i = 0.f, mB_i = -1e30f, lB_i = 0.f;
#pragma unroll
  for (int n = 0; n < 4; ++n) {
    oA[n] = (floatx4){0.f, 0.f, 0.f, 0.f};
    oB[n] = (floatx4){0.f, 0.f, 0.f, 0.f};
  }

  // staging: 256 threads cover 64 rows x 8 chunks twice (rows r0, r0+32);
  // same &7 -> same swizzled slot sl.  16B chunk g.
  int r0 = tid >> 3, g = tid & 7;      // r0 0..31
  int r1 = r0 + 32;
  int e0 = g * 8;                      // global element offset of chunk g
  int sl = (g ^ (r0 & 7)) * 8;         // swizzled LDS slot (element offset)
  int fsw = l15 & 7;                   // fragment-read swizzle
  int c0 = (quad ^ fsw) * 8;           // slot of global chunk quad
  int c1 = ((quad + 4) ^ fsw) * 8;     // slot of global chunk quad+4

  short8 pk0, pk1, pv0, pv1;

  // prologue: load kt=0, write buf0, issue loads kt=1 (fly across barrier)
  {
    const unsigned short* kp = K + base;
    const unsigned short* vp = Vt + base;
    pk0 = *(const short8*)(kp + r0 * 64 + e0);
    pk1 = *(const short8*)(kp + r1 * 64 + e0);
    pv0 = *(const short8*)(vp + (size_t)r0 * 2048 + e0);
    pv1 = *(const short8*)(vp + (size_t)r1 * 2048 + e0);
  }
  *(short8*)(lK[0] + r0 * 64 + sl) = pk0;
  *(short8*)(lK[0] + r1 * 64 + sl) = pk1;
  *(short8*)(lV[0] + r0 * 64 + sl) = pv0;
  *(short8*)(lV[0] + r1 * 64 + sl) = pv1;
  {  // NT >= 17, kt=1 always exists
    const unsigned short* kp = K + base + 4096;
    const unsigned short* vp = Vt + base + 64;
    pk0 = *(const short8*)(kp + r0 * 64 + e0);
    pk1 = *(const short8*)(kp + r1 * 64 + e0);
    pv0 = *(const short8*)(vp + (size_t)r0 * 2048 + e0);
    pv1 = *(const short8*)(vp + (size_t)r1 * 2048 + e0);
  }
  asm volatile("s_waitcnt lgkmcnt(0)" ::: "memory");
  __builtin_amdgcn_s_barrier();
  __builtin_amdgcn_sched_barrier(0);

  int qin = qoff;

  for (int kt = 0; kt < NT; ++kt) {
    int cur = kt & 1;
    bool aAct = (kt <= tA);
    const unsigned short* lKc = lK[cur];
    const unsigned short* lVc = lV[cur];

    // ---- dual-stream compute: B always, A while kt <= tA
    floatx4 scB[4], scA[4];
    qk_step(lKc, l15, c0, c1, qB0, qB1, scB);
    if (aAct) qk_step(lKc, l15, c0, c1, qA0, qA1, scA);

    sm_step(scB, mB_i, lB_i, oB, kt == NT - 1, qin, quad);
    if (aAct) sm_step(scA, mA_i, lA_i, oA, kt == tA, qin, quad);

    pv_step(scB, oB, lP[wave * 2], lVc, l15, quad, c0, c1);
    if (aAct) pv_step(scA, oA, lP[wave * 2 + 1], lVc, l15, quad, c0, c1);

    if (kt + 1 < NT) {
      // write next tile (regs hold kt+1 data) into the other buffer
      unsigned short* wK = lK[cur ^ 1];
      unsigned short* wV = lV[cur ^ 1];
      *(short8*)(wK + r0 * 64 + sl) = pk0;
      *(short8*)(wK + r1 * 64 + sl) = pk1;
      *(short8*)(wV + r0 * 64 + sl) = pv0;
      *(short8*)(wV + r1 * 64 + sl) = pv1;
      if (kt + 2 < NT) {  // issue loads for kt+2; consumed end of next iter
        const unsigned short* kp = K + base + (size_t)(kt + 2) * 4096;
        const unsigned short* vp = Vt + base + (size_t)(kt + 2) * 64;
        pk0 = *(const short8*)(kp + r0 * 64 + e0);
        pk1 = *(const short8*)(kp + r1 * 64 + e0);
        pv0 = *(const short8*)(vp + (size_t)r0 * 2048 + e0);
        pv1 = *(const short8*)(vp + (size_t)r1 * 2048 + e0);
      }
      // drain my ds reads+writes, then raw barrier (vmcnt NOT drained:
      // the kt+2 loads stay in flight across it)
      asm volatile("s_waitcnt lgkmcnt(0)" ::: "memory");
      __builtin_amdgcn_s_barrier();
      __builtin_amdgcn_sched_barrier(0);
    }
  }

  // ---- epilogue: per-lane 1/l, packed b64 stores for both streams
  int b = bh >> 4, hh = bh & 15;
  {
    float inv = 1.f / lB_i;
    int s = tB * 64 + qoff;
    size_t orow = (size_t)(b * 2048 + s) * 1024 + hh * 64;
#pragma unroll
    for (int n = 0; n < 4; ++n) {
      uint2 ov;
      ov.x = pk2bf(oB[n][0] * inv, oB[n][1] * inv);
      ov.y = pk2bf(oB[n][2] * inv, oB[n][3] * inv);
      *(uint2*)(Oc + orow + n * 16 + quad * 4) = ov;
    }
  }
  {
    float inv = 1.f / lA_i;
    int s = tA * 64 + qoff;
    size_t orow = (size_t)(b * 2048 + s) * 1024 + hh * 64;
#pragma unroll
    for (int n = 0; n < 4; ++n) {
      uint2 ov;
      ov.x = pk2bf(oA[n][0] * inv, oA[n][1] * inv);
      ov.y = pk2bf(oA[n][2] * inv, oA[n][3] * inv);
      *(uint2*)(Oc + orow + n * 16 + quad * 4) = ov;
    }
  }
}

// ---------------------------------------------------------------------------
extern "C" void kernel_launch(void* const* d_in, const int* in_sizes, int n_in,
                              void* d_out, int out_size, void* d_ws, size_t ws_size,
                              hipStream_t stream) {
  const float* x  = (const float*)d_in[0];
  const int* tokpos = (const int*)d_in[1];
  const float* Wq = (const float*)d_in[2];
  const float* Wk = (const float*)d_in[3];
  const float* Wv = (const float*)d_in[4];
  const float* Wo = (const float*)d_in[5];
  float* out = (float*)d_out;

  float* ws = (float*)d_ws;
  float* ctab = ws;
  float* stab = ctab + 65536;
  unsigned short* u = (unsigned short*)(stab + 65536);
  unsigned short* Qb  = u;
  unsigned short* Kb  = Qb + 4194304;
  unsigned short* Vb  = Kb + 4194304;   // transposed [bh][d][s]
  unsigned short* Oc  = Vb + 4194304;
  unsigned short* xb  = Oc + 4194304;
  unsigned short* Wqb = xb + 4194304;
  unsigned short* Wkb = Wqb + 1048576;
  unsigned short* Wvb = Wkb + 1048576;
  unsigned short* Wob = Wvb + 1048576;

  cvt_all<<<dim3(4096, 6), 256, 0, stream>>>(
      (const float4*)x, (const float4*)Wq, (const float4*)Wk,
      (const float4*)Wv, (const float4*)Wo,
      (ushort4*)xb, (ushort4*)Wqb, (ushort4*)Wkb, (ushort4*)Wvb, (ushort4*)Wob,
      tokpos, ctab, stab);

  qkv_mfma<<<dim3(64, 8, 3), 256, 0, stream>>>(
      xb, Wqb, Wkb, Wvb, ctab, stab, Qb, Kb, Vb);
  attn_flash<<<dim3(512), 256, 0, stream>>>(Qb, Kb, Vb, Oc);
  oproj_mfma<<<dim3(64, 8), 256, 0, stream>>>(Oc, Wob, out);
}